// Round 4
// baseline (801.338 us; speedup 1.0000x reference)
//
#include <hip/hip_runtime.h>

// NeighborAttention fused, round 5: barrier-free K-loop, no LDS staging,
// tile loop kept rolled (#pragma unroll 1) to bound code size / compile time.
// Each wave (= head) loads its MFMA A-fragments directly from global fp32
// (L1/L2 absorbs the 4x cross-wave re-read), converting to bf16 in-register.
// No staging register batches (round-3 spilled 179 MB scratch), only 2
// barriers per block.
// B=4,N=2000,K=30,H=128,HEADS=4,D=32,NUM_IN=256. fp32 in/out, bf16 MFMA.

#define KNB 30
#define HH 128
#define NUMIN 256
#define TOK 8000
#define TOTROW (TOK*KNB)    // 240000
#define TILES 4             // tiles per block, 2 tokens each
#define TOKB (2*TILES)      // 8 tokens per block
#define NBLK (TOK/TOKB)     // 1000

typedef __bf16 bf16x8 __attribute__((ext_vector_type(8)));
typedef __bf16 bf16x4_t __attribute__((ext_vector_type(4)));
typedef float f32x4 __attribute__((ext_vector_type(4)));

// ws layout (bf16): [W_K1 16384][W_K2 16384][W_V 32768]
__global__ __launch_bounds__(256) void conv_w_kernel(
    const float* __restrict__ wk1, const float* __restrict__ wk2,
    const float* __restrict__ wv, __bf16* __restrict__ ws) {
  int e = (blockIdx.x * 256 + threadIdx.x) * 4;
  const float* src; int off;
  if (e < 16384)      { src = wk1; off = e; }
  else if (e < 32768) { src = wk2; off = e - 16384; }
  else                { src = wv;  off = e - 32768; }
  float4 v = *(const float4*)(src + off);
  bf16x4_t o4;
  o4.x = (__bf16)v.x; o4.y = (__bf16)v.y; o4.z = (__bf16)v.z; o4.w = (__bf16)v.w;
  *(bf16x4_t*)(ws + e) = o4;
}

__device__ inline bf16x8 cvt8(const float* __restrict__ p) {
  float4 a0 = *(const float4*)p;
  float4 a1 = *(const float4*)(p + 4);
  bf16x8 r;
  r[0] = (__bf16)a0.x; r[1] = (__bf16)a0.y; r[2] = (__bf16)a0.z; r[3] = (__bf16)a0.w;
  r[4] = (__bf16)a1.x; r[5] = (__bf16)a1.y; r[6] = (__bf16)a1.z; r[7] = (__bf16)a1.w;
  return r;
}

__global__ __launch_bounds__(256, 3) void na_main_kernel(
    const float* __restrict__ h_V, const float* __restrict__ h_EV,
    const float* __restrict__ h_KV, const float* __restrict__ h_KE,
    const float* __restrict__ maskp, const float* __restrict__ W_Q,
    const float* __restrict__ W_O, const __bf16* __restrict__ bW,
    float* __restrict__ out) {
  __shared__ float sQ[TOKB][HH];       // 4 KB
  __shared__ float sU[TOKB][HH];       // 4 KB
  __shared__ float sMask[TOKB][32];    // 1 KB

  const int tid = threadIdx.x;
  const int lane = tid & 63;
  const int wave = tid >> 6;           // wave == head
  const int m = lane & 15;
  const int quad = lane >> 4;
  const int tok0 = blockIdx.x * TOKB;

  const __bf16* bWK1 = bW;
  const __bf16* bWK2 = bW + 16384;
  const __bf16* bWV  = bW + 32768;

  f32x4 accA[4][2], accB[4][2];
  const f32x4 fzero = {0.f, 0.f, 0.f, 0.f};

  // One wave computes cols [wave*32, wave*32+32) for 64 A-rows (4 M-tiles).
  // A-fragments come straight from global fp32, converted to bf16 in-regs.
  auto gemm_g = [&](const __bf16* gW, int ldw, int kw, const float* gA,
                    int lda, int ka, int r0, f32x4 (*acc)[2]) {
#pragma unroll
    for (int ks = 0; ks < 4; ks++) {
      const int kcW = kw + ks * 32 + quad * 8;
      bf16x8 b0 = *(const bf16x8*)(gW + (wave * 32 + m) * ldw + kcW);
      bf16x8 b1 = *(const bf16x8*)(gW + (wave * 32 + 16 + m) * ldw + kcW);
#pragma unroll
      for (int mt = 0; mt < 4; mt++) {
        int rr = r0 + mt * 16 + m;
        if (rr > TOTROW - 1) rr = TOTROW - 1;   // array-end clamp only
        const float* ap = gA + (long)rr * lda + ka + ks * 32 + quad * 8;
        bf16x8 a = cvt8(ap);
        acc[mt][0] = __builtin_amdgcn_mfma_f32_16x16x32_bf16(a, b0, acc[mt][0], 0, 0, 0);
        acc[mt][1] = __builtin_amdgcn_mfma_f32_16x16x32_bf16(a, b1, acc[mt][1], 0, 0, 0);
      }
    }
  };

  // ---- prologue: mask + Q projection (all 8 tokens, 4-way ILP) ----
  if (tid < TOKB * KNB)
    sMask[tid / KNB][tid % KNB] = maskp[(long)tok0 * KNB + tid];
  {
    const int o = tid & 127, g = tid >> 7;
    const float4* wq = (const float4*)(W_Q + o * HH);
    float qa[4] = {0.f, 0.f, 0.f, 0.f};
#pragma unroll
    for (int j = 0; j < 32; j++) {
      float4 b = wq[j];
#pragma unroll
      for (int t = 0; t < 4; t++) {
        float4 a = *(const float4*)(h_V + (long)(tok0 + g * 4 + t) * HH + j * 4);
        qa[t] += a.x * b.x + a.y * b.y + a.z * b.z + a.w * b.w;
      }
    }
#pragma unroll
    for (int t = 0; t < 4; t++) sQ[g * 4 + t][o] = qa[t];
  }
  __syncthreads();

  // ---- barrier-free per-tile loop: waves run fully decoupled.
  //      Kept rolled: bounds code size (compile-time + I-cache). ----
#pragma unroll 1
  for (int it = 0; it < TILES; ++it) {
    const int tb = 2 * it;
    const int r0 = (tok0 + 2 * it) * KNB;
    float lg[4][4];

    // K1 = h_KE @ W_K1^T  (this wave's 32 cols)
#pragma unroll
    for (int mt = 0; mt < 4; mt++) { accA[mt][0] = fzero; accA[mt][1] = fzero; }
    gemm_g(bWK1, HH, 0, h_KE, HH, 0, r0, accA);

    // K2 = h_KV @ W_K2^T
#pragma unroll
    for (int mt = 0; mt < 4; mt++) { accB[mt][0] = fzero; accB[mt][1] = fzero; }
    gemm_g(bWK2, HH, 0, h_KV, HH, 0, r0, accB);

    // P = K1 * K2 elementwise
#pragma unroll
    for (int mt = 0; mt < 4; mt++) {
      accA[mt][0] *= accB[mt][0];
      accA[mt][1] *= accB[mt][1];
    }

    // ---- logits: dot with Q over d (in-wave reduction across cols) ----
    {
      float q0[2], q1[2];
#pragma unroll
      for (int nt = 0; nt < 2; nt++) {
        q0[nt] = sQ[tb][wave * 32 + nt * 16 + m];
        q1[nt] = sQ[tb + 1][wave * 32 + nt * 16 + m];
      }
#pragma unroll
      for (int mt = 0; mt < 4; mt++)
#pragma unroll
        for (int r = 0; r < 4; r++) {
          int R = mt * 16 + quad * 4 + r;
          float qa0 = (R < 30) ? q0[0] : q1[0];
          float qa1 = (R < 30) ? q0[1] : q1[1];
          lg[mt][r] = accA[mt][0][r] * qa0 + accA[mt][1][r] * qa1;
        }
#pragma unroll
      for (int d = 1; d < 16; d <<= 1)
#pragma unroll
        for (int mt = 0; mt < 4; mt++)
#pragma unroll
          for (int r = 0; r < 4; r++)
            lg[mt][r] += __shfl_xor(lg[mt][r], d);

      // masked softmax (wave-local, quad-reduce); attend overwrites lg
      float mx0 = -3.0e38f, mx1 = -3.0e38f;
#pragma unroll
      for (int mt = 0; mt < 4; mt++)
#pragma unroll
        for (int r = 0; r < 4; r++) {
          int R = mt * 16 + quad * 4 + r;
          if (R < 60) {
            int t = R >= 30, k = R - 30 * t;
            float l = (sMask[tb + t][k] > 0.f) ? lg[mt][r] * 0.03125f : -3.0e38f;
            lg[mt][r] = l;
            if (t == 0) mx0 = fmaxf(mx0, l); else mx1 = fmaxf(mx1, l);
          } else lg[mt][r] = -3.0e38f;
        }
      mx0 = fmaxf(mx0, __shfl_xor(mx0, 16)); mx0 = fmaxf(mx0, __shfl_xor(mx0, 32));
      mx1 = fmaxf(mx1, __shfl_xor(mx1, 16)); mx1 = fmaxf(mx1, __shfl_xor(mx1, 32));
      float s0 = 0.f, s1 = 0.f;
#pragma unroll
      for (int mt = 0; mt < 4; mt++)
#pragma unroll
        for (int r = 0; r < 4; r++) {
          int R = mt * 16 + quad * 4 + r;
          float e = 0.f;
          if (R < 60) {
            int t = R >= 30, k = R - 30 * t;
            if (sMask[tb + t][k] > 0.f) {
              float mxt = (t == 0) ? mx0 : mx1;
              e = __expf(lg[mt][r] - mxt);
            }
            if (t == 0) s0 += e; else s1 += e;
          }
          lg[mt][r] = e;
        }
      s0 += __shfl_xor(s0, 16); s0 += __shfl_xor(s0, 32);
      s1 += __shfl_xor(s1, 16); s1 += __shfl_xor(s1, 32);
      float inv0 = (s0 > 0.f) ? 1.f / s0 : 0.f;
      float inv1 = (s1 > 0.f) ? 1.f / s1 : 0.f;
#pragma unroll
      for (int mt = 0; mt < 4; mt++)
#pragma unroll
        for (int r = 0; r < 4; r++) {
          int R = mt * 16 + quad * 4 + r;
          lg[mt][r] *= (R < 30) ? inv0 : inv1;
        }
    }

    // V = h_EV @ W_V^T (K = 256, two halves accumulate)
#pragma unroll
    for (int mt = 0; mt < 4; mt++) { accB[mt][0] = fzero; accB[mt][1] = fzero; }
    gemm_g(bWV, NUMIN, 0,   h_EV, NUMIN, 0,   r0, accB);
    gemm_g(bWV, NUMIN, 128, h_EV, NUMIN, 128, r0, accB);

    // ---- aggregation: attend . V over neighbors, quad-reduce, write sU ----
    {
      float u00 = 0.f, u01 = 0.f, u10 = 0.f, u11 = 0.f;
#pragma unroll
      for (int mt = 0; mt < 4; mt++)
#pragma unroll
        for (int r = 0; r < 4; r++) {
          int R = mt * 16 + quad * 4 + r;
          if (R < 30) {
            u00 += lg[mt][r] * accB[mt][0][r];
            u01 += lg[mt][r] * accB[mt][1][r];
          } else if (R < 60) {
            u10 += lg[mt][r] * accB[mt][0][r];
            u11 += lg[mt][r] * accB[mt][1][r];
          }
        }
      u00 += __shfl_xor(u00, 16); u00 += __shfl_xor(u00, 32);
      u01 += __shfl_xor(u01, 16); u01 += __shfl_xor(u01, 32);
      u10 += __shfl_xor(u10, 16); u10 += __shfl_xor(u10, 32);
      u11 += __shfl_xor(u11, 16); u11 += __shfl_xor(u11, 32);
      if (quad == 0) {
        sU[tb][wave * 32 + m]          = u00;
        sU[tb][wave * 32 + 16 + m]     = u01;
        sU[tb + 1][wave * 32 + m]      = u10;
        sU[tb + 1][wave * 32 + 16 + m] = u11;
      }
    }
  }
  __syncthreads();

  // ---- epilogue: out = h_upd @ W_O^T for all 8 tokens, 4-way ILP ----
  {
    const int o = tid & 127, g = tid >> 7;
    const float4* wo = (const float4*)(W_O + o * HH);
    float r[4] = {0.f, 0.f, 0.f, 0.f};
#pragma unroll
    for (int j = 0; j < 32; j++) {
      float4 b = wo[j];
#pragma unroll
      for (int t = 0; t < 4; t++) {
        float4 a = *(const float4*)(&sU[g * 4 + t][j * 4]);
        r[t] += a.x * b.x + a.y * b.y + a.z * b.z + a.w * b.w;
      }
    }
#pragma unroll
    for (int t = 0; t < 4; t++)
      out[(long)(tok0 + g * 4 + t) * HH + o] = r[t];
  }
}

extern "C" void kernel_launch(void* const* d_in, const int* in_sizes, int n_in,
                              void* d_out, int out_size, void* d_ws, size_t ws_size,
                              hipStream_t stream) {
  const float* h_V  = (const float*)d_in[0];
  const float* h_EV = (const float*)d_in[1];
  const float* h_KV = (const float*)d_in[2];
  const float* h_KE = (const float*)d_in[3];
  const float* mask = (const float*)d_in[4];
  const float* W_Q  = (const float*)d_in[5];
  const float* W_K1 = (const float*)d_in[6];
  const float* W_K2 = (const float*)d_in[7];
  const float* W_V  = (const float*)d_in[8];
  const float* W_O  = (const float*)d_in[9];
  __bf16* bW = (__bf16*)d_ws;

  conv_w_kernel<<<64, 256, 0, stream>>>(W_K1, W_K2, W_V, bW);
  na_main_kernel<<<NBLK, 256, 0, stream>>>(h_V, h_EV, h_KV, h_KE, mask,
                                           W_Q, W_O, bW, (float*)d_out);
}